// Round 8
// baseline (1127964.746 us; speedup 1.0000x reference)
//
#include <hip/hip_runtime.h>

#define BDIM 256   // batch
#define SDIM 512   // seq len
#define HDIM 512   // hidden
#define VDIM 128   // vocab
#define NBG 8      // batch groups
#define BB 32      // batch per group
#define HHU 16     // hidden units per block
#define WIHP 72    // col-major W_ih pitch (halfwords) per vocab row
#define NT 320     // 5 waves: w0,w1 gates; w2,w3 stage help; w4 proj
#define HBQ_SLOT 32768  // qwords per (buf,medium) slot = 256 KiB

typedef unsigned short ushort_t;
typedef unsigned long long u64_t;
typedef __attribute__((ext_vector_type(8))) short bf16x8;
typedef __attribute__((ext_vector_type(4))) float f32x4;
typedef __attribute__((ext_vector_type(16))) float f32x16;

__device__ __forceinline__ ushort_t f2bf(float x) {
  unsigned u = __builtin_bit_cast(unsigned, x);
  u += 0x7fffu + ((u >> 16) & 1u);
  return (ushort_t)(u >> 16);
}
__device__ __forceinline__ float bf2f(ushort_t b) {
  unsigned u = ((unsigned)b) << 16;
  return __builtin_bit_cast(float, u);
}
__device__ __forceinline__ float sigmoidf_(float x) { return 1.f / (1.f + __expf(-x)); }
__device__ __forceinline__ float tanhf_(float x) { return 2.f / (1.f + __expf(-2.f * x)) - 1.f; }

// ---- XCD-L2 (sc0) access helpers: bypass CU L1, coherent at the XCD's L2 ---
__device__ __forceinline__ void l2_store_u64(u64_t* p, u64_t v) {
  asm volatile("global_store_dwordx2 %0, %1, off sc0" ::"v"(p), "v"(v) : "memory");
}
__device__ __forceinline__ void l2_store_u32(unsigned* p, unsigned v) {
  asm volatile("global_store_dword %0, %1, off sc0" ::"v"(p), "v"(v) : "memory");
}
__device__ __forceinline__ unsigned l2_load_u32(const unsigned* p) {
  unsigned v;
  asm volatile("global_load_dword %0, %1, off sc0\n\ts_waitcnt vmcnt(0)"
               : "=v"(v) : "v"(p) : "memory");
  return v;
}

// ---- weight loading (unchanged from R4) -----------------------------------
__device__ __forceinline__ void load_afrag32(bf16x8* af, const float* Whh, int hs, int w,
                                             int lane) {
  const int m = lane & 31, half = lane >> 5;
  const int g = m & 3, hh = (m >> 2) & 1, s = m >> 3;
  const int gr = g * HDIM + hs * HHU + w * 8 + 2 * s + hh;
  const float* row = Whh + (size_t)gr * HDIM + half * 8;
#pragma unroll
  for (int kt = 0; kt < 32; ++kt) {
    const float4 f0 = *(const float4*)(row + kt * 16);
    const float4 f1 = *(const float4*)(row + kt * 16 + 4);
    bf16x8 v;
    v[0] = (short)f2bf(f0.x); v[1] = (short)f2bf(f0.y);
    v[2] = (short)f2bf(f0.z); v[3] = (short)f2bf(f0.w);
    v[4] = (short)f2bf(f1.x); v[5] = (short)f2bf(f1.y);
    v[6] = (short)f2bf(f1.z); v[7] = (short)f2bf(f1.w);
    af[kt] = v;
  }
}
__device__ __forceinline__ void load_afrag16(bf16x8* af, const float* W, int gr, int ko,
                                             bool valid) {
  const float* row = W + (size_t)gr * HDIM;
#pragma unroll
  for (int kt = 0; kt < 16; ++kt) {
    bf16x8 v;
    if (valid) {
      const float4 f0 = *(const float4*)(row + kt * 32 + ko);
      const float4 f1 = *(const float4*)(row + kt * 32 + ko + 4);
      v[0] = (short)f2bf(f0.x); v[1] = (short)f2bf(f0.y);
      v[2] = (short)f2bf(f0.z); v[3] = (short)f2bf(f0.w);
      v[4] = (short)f2bf(f1.x); v[5] = (short)f2bf(f1.y);
      v[6] = (short)f2bf(f1.z); v[7] = (short)f2bf(f1.w);
    } else {
#pragma unroll
      for (int j = 0; j < 8; ++j) v[j] = 0;
    }
    af[kt] = v;
  }
}
__device__ __forceinline__ void load_wih_cm(ushort_t* wih_s, float* bias_s, const float* Wih,
                                            const float* bi, const float* bh, int hs,
                                            int tid) {
  for (int c = tid; c < 128 * 64; c += NT) {
    int v = c & 127, col = c >> 7;
    int g = col & 3, s = (col >> 2) & 3, hh = (col >> 4) & 1, wv = col >> 5;
    int gr = g * HDIM + hs * HHU + wv * 8 + 2 * s + hh;
    wih_s[v * WIHP + col] = f2bf(Wih[(size_t)gr * VDIM + v]);
  }
  if (tid < 64) {
    int col = tid;
    int g = col & 3, s = (col >> 2) & 3, hh = (col >> 4) & 1, wv = col >> 5;
    int gr = g * HDIM + hs * HHU + wv * 8 + 2 * s + hh;
    bias_s[col] = bi[gr] + bh[gr];
  }
}

// Sync (R8 = R4 choreography, DUAL-PUBLISH medium):
//  Producers ALWAYS publish h+flags twice: sc0 copy (XCD-L2) and agent copy
//  (LLC), to disjoint buffers. Consumers independently pick a medium:
//  fast (sc0) iff (a) HW_REG_XCC_ID uniform across the bg's 32 blocks AND
//  (b) an sc0 ping-pong probe succeeds; any timeout => slow. Mixed decisions
//  are CORRECT (both copies always exist); a wrong 'fast' only costs speed is
//  impossible since both checks must pass on live sc0 reads. Spin caps are
//  small so a broken medium fails fast (absmax) instead of wedging the GPU.
__global__ void __launch_bounds__(NT, 1) lstm_kernel(
    const int* __restrict__ C_idx, const int* __restrict__ E,
    const float* __restrict__ eWih, const float* __restrict__ eWhh,
    const float* __restrict__ ebi, const float* __restrict__ ebh,
    const float* __restrict__ dWih, const float* __restrict__ dWhh,
    const float* __restrict__ dbi, const float* __restrict__ dbh,
    const float* __restrict__ pW, const float* __restrict__ pb,
    unsigned* flagsL2, unsigned* flagsLLC, unsigned* xcdmap, unsigned* probeb,
    u64_t* hbq, ushort_t* logits) {
  __shared__ ushort_t h_s[BB * HDIM];       // 32 KB, octet-swizzled
  __shared__ ushort_t wih_s[VDIM * WIHP];   // 18 KB, col-major
  __shared__ float bias_s[64];
  __shared__ float pb_s[4];
  __shared__ int idx_s[2][BB];
  __shared__ int fast_s;

  const int tid = threadIdx.x;
  const int w = tid >> 6;
  const int lane = tid & 63;
  const int bg = blockIdx.x & 7;  // one batch group per XCD under round-robin
  const int hs = blockIdx.x >> 3;

  // ---- publish co-location evidence (both mediums) ----
  unsigned xcc;
  asm volatile("s_getreg_b32 %0, hwreg(20, 0, 4)" : "=s"(xcc));  // HW_REG_XCC_ID
  if (tid == 0) {
    l2_store_u32(&probeb[bg * 32 + hs], 0xC0DE0000u | (unsigned)blockIdx.x);
    __hip_atomic_store(&xcdmap[bg * 32 + hs], xcc + 1, __ATOMIC_RELAXED,
                       __HIP_MEMORY_SCOPE_AGENT);
  }

  // persistent per-lane state
  bf16x8 afrag[32];  // gate waves: 32 K-chunks (128 VGPR). proj wave: 16 used.
  float cst[4] = {0.f, 0.f, 0.f, 0.f};
  if (w < 2) {
    load_afrag32(afrag, eWhh, hs, w, lane);
  } else if (w == 4) {
    load_afrag16(afrag, pW, hs * 4 + (lane & 15), (lane >> 4) * 8, (lane & 15) < 4);
  }
  load_wih_cm(wih_s, bias_s, eWih, ebi, ebh, hs, tid);
  if (tid < 4) pb_s[tid] = pb[hs * 4 + tid];
  if (tid < BB) idx_s[0][tid] = C_idx[(size_t)(bg * BB + tid) * SDIM];

  // ---- fast/slow decision (timeouts resolve toward SLOW = always-correct) --
  if (w == 0) {
    bool ok = true;
    if (lane < 32) {
      const unsigned expv = 0xC0DE0000u | (unsigned)(lane * 8 + bg);
      unsigned v = 0;
      int r = 0;
      do {
        v = l2_load_u32(&probeb[bg * 32 + lane]);
      } while (v != expv && ++r < (1 << 13));
      unsigned u = 0;
      r = 0;
      do {
        u = __hip_atomic_load(&xcdmap[bg * 32 + lane], __ATOMIC_RELAXED,
                              __HIP_MEMORY_SCOPE_AGENT);
      } while (u == 0 && ++r < (1 << 15));
      ok = (v == expv) && (u == xcc + 1);
    }
    unsigned long long bal = __ballot(ok);
    if (lane == 0) fast_s = ((bal & 0xFFFFFFFFull) == 0xFFFFFFFFull) ? 1 : 0;
  }
  __syncthreads();
  const bool fast = (fast_s != 0);

  for (int t = 0; t <= 1024; ++t) {
    const bool last = (t == 1024);
    const bool proj_on = (t >= 513);

    if (t == 512) {  // phase switch (after trailing barrier of t=511)
      if (w < 2) load_afrag32(afrag, dWhh, hs, w, lane);
      load_wih_cm(wih_s, bias_s, dWih, dbi, dbh, hs, tid);
    }
    // prefetch idx for step t+1 (load now, LDS-write after stage barrier)
    int myidx = 0;
    const bool pf = (tid < BB) && (t + 1 < 1024);
    if (pf) {
      int tn = t + 1;
      myidx = (tn >= 512) ? E[(size_t)(bg * BB + tid) * (SDIM + 1) + (tn - 512)]
                          : C_idx[(size_t)(bg * BB + tid) * SDIM + tn];
    }

    // poll: w0's 32 lanes watch the bg's 32 per-block flags (chosen medium)
    if (t > 0 && w == 0 && lane < BB) {
      const unsigned tgt = (unsigned)t;
      int rounds = 0;
      if (fast) {
        const unsigned* fp = flagsL2 + bg * BB + lane;
        while (l2_load_u32(fp) < tgt) {
          if (++rounds > (1 << 14)) break;  // fail-fast, never hit when healthy
        }
      } else {
        const unsigned* fp = flagsLLC + bg * BB + lane;
        while (__hip_atomic_load(fp, __ATOMIC_RELAXED, __HIP_MEMORY_SCOPE_AGENT) < tgt) {
          if (++rounds > (1 << 14)) break;
        }
      }
    }
    __syncthreads();

    // stage h[32,512] bf16 (4096 u64) -> swizzled LDS, all 320 threads
    {
      const u64_t* src = hbq + ((size_t)(t & 1) * 2 + (fast ? 0 : 1)) * HBQ_SLOT +
                         (size_t)(bg * BB) * 128;
      u64_t tmp[13];
      if (fast) {
#pragma unroll
        for (int k = 0; k < 13; ++k) {
          int c = tid + k * NT;
          if (c < 4096)
            asm volatile("global_load_dwordx2 %0, %1, off sc0"
                         : "=v"(tmp[k]) : "v"(src + c) : "memory");
        }
        asm volatile("s_waitcnt vmcnt(0)" ::: "memory");
      } else {
#pragma unroll
        for (int k = 0; k < 13; ++k) {
          int c = tid + k * NT;
          if (c < 4096)
            tmp[k] = __hip_atomic_load(src + c, __ATOMIC_RELAXED,
                                       __HIP_MEMORY_SCOPE_AGENT);
        }
      }
#pragma unroll
      for (int k = 0; k < 13; ++k) {
        int c = tid + k * NT;
        if (c < 4096) {
          int m = c >> 7, k7 = c & 127;
          int p = (k7 >> 1) ^ (m & 7);
          *(u64_t*)&h_s[m * HDIM + p * 8 + (k7 & 1) * 4] = tmp[k];
        }
      }
    }
    __syncthreads();
    if (pf) idx_s[(t + 1) & 1][tid] = myidx;

    if (w < 2 && !last) {
      // gates: D[64 gate-rows x 32 batches], 2 waves of mfma_32x32x16
      const int b = lane & 31, half = lane >> 5;
      const int w2h = w * 2 + half;
      f32x16 acc;
      {
        const int id0 = idx_s[t & 1][b];
        const ushort_t* wp = &wih_s[id0 * WIHP + w2h * 16];
        bf16x8 g0 = *(const bf16x8*)wp;
        bf16x8 g1 = *(const bf16x8*)(wp + 8);
#pragma unroll
        for (int r = 0; r < 8; ++r) {
          acc[r] = bias_s[w2h * 16 + r] + bf2f((ushort_t)g0[r]);
          acc[8 + r] = bias_s[w2h * 16 + 8 + r] + bf2f((ushort_t)g1[r]);
        }
      }
      const ushort_t* hrow = &h_s[b * HDIM];
      const int bx = b & 7;
#pragma unroll
      for (int kt = 0; kt < 32; ++kt) {
        bf16x8 bfr = *(const bf16x8*)(hrow + ((kt * 2 + half) ^ bx) * 8);
        acc = __builtin_amdgcn_mfma_f32_32x32x16_bf16(afrag[kt], bfr, acc, 0, 0, 0);
      }
      // acc[s*4+g]: gate g, unit 2s+half (of wave's 8 units), batch b
      unsigned hv[4];
#pragma unroll
      for (int s = 0; s < 4; ++s) {
        float ig = acc[s * 4 + 0], fg = acc[s * 4 + 1];
        float gg = acc[s * 4 + 2], og = acc[s * 4 + 3];
        float cn = sigmoidf_(fg) * cst[s] + sigmoidf_(ig) * tanhf_(gg);
        cst[s] = cn;
        hv[s] = f2bf(sigmoidf_(og) * tanhf_(cn));
      }
      u64_t own = (u64_t)hv[0] | ((u64_t)hv[1] << 16) | ((u64_t)hv[2] << 32) |
                  ((u64_t)hv[3] << 48);
      u64_t par = (u64_t)__shfl_xor((long long)own, 32, 64);  // partner: half^1
      u64_t out = 0;
#pragma unroll
      for (int j = 0; j < 4; ++j) {  // pack units 4*half+j of this wave's group
        int u4 = 4 * half + j;
        int sidx = 2 * half + (j >> 1);
        u64_t sv = ((u4 & 1) == half) ? own : par;
        out |= ((sv >> (16 * sidx)) & 0xFFFFull) << (16 * j);
      }
      // dual-publish: sc0 copy (slot med=0) + agent copy (slot med=1)
      const size_t qi = ((size_t)((t + 1) & 1) * 2) * HBQ_SLOT +
                        (size_t)(bg * BB + b) * 128 + hs * 4 + w * 2 + half;
      l2_store_u64(hbq + qi, out);
      __hip_atomic_store(hbq + qi + HBQ_SLOT, out, __ATOMIC_RELAXED,
                         __HIP_MEMORY_SCOPE_AGENT);
    } else if (w == 4 && proj_on) {
      // proj: vocab rows hs*4..hs*4+3 x 32 batches, 2 tiles of mfma_16x16x32
      const int n = lane & 15, q = lane >> 4;
      f32x4 acc0 = {0.f, 0.f, 0.f, 0.f};
      f32x4 acc1 = {0.f, 0.f, 0.f, 0.f};
#pragma unroll
      for (int kt = 0; kt < 16; ++kt) {
        const int po = ((kt * 4 + q) ^ (n & 7)) * 8;
        bf16x8 b0 = *(const bf16x8*)&h_s[n * HDIM + po];
        bf16x8 b1 = *(const bf16x8*)&h_s[(16 + n) * HDIM + po];
        acc0 = __builtin_amdgcn_mfma_f32_16x16x32_bf16(afrag[kt], b0, acc0, 0, 0, 0);
        acc1 = __builtin_amdgcn_mfma_f32_16x16x32_bf16(afrag[kt], b1, acc1, 0, 0, 0);
      }
      if (q == 0) {  // rows 0..3 = reg = vocab hs*4+reg
        const int ld = t - 513;
        u64_t q0 = 0, q1 = 0;
#pragma unroll
        for (int r = 0; r < 4; ++r) {
          q0 |= (u64_t)f2bf(acc0[r] + pb_s[r]) << (16 * r);
          q1 |= (u64_t)f2bf(acc1[r] + pb_s[r]) << (16 * r);
        }
        u64_t* lq = (u64_t*)logits;
        const size_t base = ((size_t)ld * BDIM + bg * BB) * 32 + hs;
        lq[base + (size_t)n * 32] = q0;
        lq[base + (size_t)(16 + n) * 32] = q1;
      }
    }
    __syncthreads();  // drains vmcnt(0) per wave: BOTH h copies are committed
    if (!last && tid == 0) {
      l2_store_u32(&flagsL2[bg * BB + hs], (unsigned)(t + 1));
      __hip_atomic_store(&flagsLLC[bg * BB + hs], (unsigned)(t + 1), __ATOMIC_RELAXED,
                         __HIP_MEMORY_SCOPE_AGENT);
    }
  }
}

__global__ void loss_kernel(const ushort_t* __restrict__ logits, const int* __restrict__ E,
                            float* __restrict__ partial) {
  const int t = blockIdx.x;   // 512
  const int b = threadIdx.x;  // 256
  const ushort_t* row = logits + ((size_t)t * BDIM + b) * VDIM;
  float mx = -3.0e38f;
  for (int k = 0; k < VDIM; ++k) mx = fmaxf(mx, bf2f(row[k]));
  float se = 0.f;
  for (int k = 0; k < VDIM; ++k) se += __expf(bf2f(row[k]) - mx);
  const int tgt = E[(size_t)b * (SDIM + 1) + t];
  float nll = (mx + __logf(se)) - bf2f(row[tgt]);
  float m = (tgt != 0) ? 1.f : 0.f;
  __shared__ float s1[BDIM];
  __shared__ float s0[BDIM];
  s1[b] = nll * m;
  s0[b] = m;
  __syncthreads();
  for (int s = 128; s > 0; s >>= 1) {
    if (b < s) {
      s1[b] += s1[b + s];
      s0[b] += s0[b + s];
    }
    __syncthreads();
  }
  if (b == 0) partial[t] = (s0[0] > 0.f) ? s1[0] / s0[0] : 0.f;
}

__global__ void reduce_kernel(const float* __restrict__ partial, float* __restrict__ out) {
  __shared__ float sm[SDIM];
  sm[threadIdx.x] = partial[threadIdx.x];
  __syncthreads();
  for (int s = 256; s > 0; s >>= 1) {
    if (threadIdx.x < s) sm[threadIdx.x] += sm[threadIdx.x + s];
    __syncthreads();
  }
  if (threadIdx.x == 0) out[0] = sm[0];
}

extern "C" void kernel_launch(void* const* d_in, const int* in_sizes, int n_in,
                              void* d_out, int out_size, void* d_ws, size_t ws_size,
                              hipStream_t stream) {
  const int* C_idx = (const int*)d_in[0];
  const int* E = (const int*)d_in[1];
  const float* eWih = (const float*)d_in[2];
  const float* eWhh = (const float*)d_in[3];
  const float* ebi = (const float*)d_in[4];
  const float* ebh = (const float*)d_in[5];
  const float* dWih = (const float*)d_in[6];
  const float* dWhh = (const float*)d_in[7];
  const float* dbi = (const float*)d_in[8];
  const float* dbh = (const float*)d_in[9];
  const float* pW = (const float*)d_in[10];
  const float* pb = (const float*)d_in[11];

  char* ws = (char*)d_ws;
  unsigned* flagsL2 = (unsigned*)ws;                    // 256*4 B
  unsigned* flagsLLC = (unsigned*)(ws + 1024);          // 256*4 B
  unsigned* xcdmap = (unsigned*)(ws + 2048);            // 256*4 B
  unsigned* probeb = (unsigned*)(ws + 3072);            // 256*4 B
  u64_t* hbq = (u64_t*)(ws + 4096);                     // 4 slots x 256 KiB = 1 MiB
  ushort_t* logits = (ushort_t*)(ws + 4096 + 1048576);  // 32 MiB
  float* partial = (float*)(ws + 4096 + 1048576 + 33554432);  // 512*4 B

  // zero flags/xcdmap/probe + BOTH medium copies of h buffer 0 (slots 0,1)
  hipMemsetAsync(d_ws, 0, 4096 + 524288, stream);
  lstm_kernel<<<256, NT, 0, stream>>>(C_idx, E, eWih, eWhh, ebi, ebh, dWih, dWhh, dbi, dbh,
                                      pW, pb, flagsL2, flagsLLC, xcdmap, probeb, hbq,
                                      logits);
  loss_kernel<<<512, 256, 0, stream>>>(logits, E, partial);
  reduce_kernel<<<1, 512, 0, stream>>>(partial, (float*)d_out);
}